// Round 3
// baseline (735.151 us; speedup 1.0000x reference)
//
#include <hip/hip_runtime.h>

// CropAndResize: image (8,256,200,200) fp32, boxes (N,4), box_ind (N,) ->
// out (N,256,14,14) fp32.
// R5 (register anchor — force 28 gathers in flight):
//  R3 (launch_bounds) and R4 (sched_barrier + arrays) both failed to move
//  VGPR past 32 -> loads never stayed in flight. This version issues each
//  group's 28 loads into 28 NAMED scalars (macro-expanded, no arrays, no
//  unroll pragmas) and anchors ALL of them as "+v" operands of one empty
//  asm volatile before the consume phase. The data dependence makes sinking
//  impossible and forces 28 simultaneously-live VGPRs; waitcnts are compiler-
//  inserted (loads are plain C loads) so there is no correctness risk.
//  Kept: counting-sort by image, chunk-major block order, bijective XCD
//  swizzle, packed LDS descriptors (int4 + float4).

#define CROP_H 14
#define CROP_W 14
#define CROP_HW (CROP_H * CROP_W)           // 196
#define C_DIM 256
#define H_DIM 200
#define W_DIM 200
#define HW (H_DIM * W_DIM)
#define PER_BOX (C_DIM * CROP_HW)           // 50176
#define BLOCK 256
#define CHUNKS 4
#define C_PER (C_DIM / CHUNKS)              // 64 channels per block
#define ELEMS (C_PER * CROP_HW)             // 12544 elements per block
#define ITERS (ELEMS / BLOCK)               // 49 (exact, no tail)
#define GRP 7                               // 49 = 7 groups of 7
#define NXCD 8

__global__ __launch_bounds__(BLOCK) void sort_boxes_kernel(
    const int* __restrict__ box_ind, int N, int* __restrict__ perm)
{
    __shared__ int cnt[8];
    __shared__ int base[8];
    const int t = threadIdx.x;
    if (t < 8) cnt[t] = 0;
    __syncthreads();
    for (int i = t; i < N; i += BLOCK) atomicAdd(&cnt[box_ind[i]], 1);
    __syncthreads();
    if (t == 0) {
        int run = 0;
        for (int b = 0; b < 8; ++b) { base[b] = run; run += cnt[b]; }
    }
    __syncthreads();
    for (int i = t; i < N; i += BLOCK) {
        const int pos = atomicAdd(&base[box_ind[i]], 1);
        perm[pos] = i;
    }
}

// Issue 4 gathers for element u of group g into named scalars.
#define GATHER(u, TL, TR, BL, BR) do {                                  \
    const int jj = t + (g * GRP + (u)) * BLOCK;                         \
    const int cc = jj / CROP_HW;                                        \
    const int pp = jj - cc * CROP_HW;                                   \
    const int4 dd = s_d[pp];                                            \
    const float* __restrict__ bc = imgb + (size_t)cc * HW + dd.x;       \
    TL = bc[0]; TR = bc[dd.y]; BL = bc[dd.z]; BR = bc[dd.z + dd.y];     \
} while (0)

// Consume element u of group g and store.
#define CONSUME(u, TL, TR, BL, BR) do {                                 \
    const int jj = t + (g * GRP + (u)) * BLOCK;                         \
    const int cc = jj / CROP_HW;                                        \
    const int pp = jj - cc * CROP_HW;                                   \
    const float4 w = s_w[pp];                                           \
    const float top_v = fmaf(TR - TL, w.y, TL);                         \
    const float bot_v = fmaf(BR - BL, w.y, BL);                         \
    float v = fmaf(bot_v - top_v, w.x, top_v);                          \
    outb[jj] = v * w.z;                                                 \
} while (0)

__global__ __launch_bounds__(BLOCK, 6) void crop_and_resize_kernel(
    const float* __restrict__ image,
    const float* __restrict__ boxes,
    const int*   __restrict__ box_ind,
    const int*   __restrict__ perm,
    float*       __restrict__ out,
    int N)
{
    __shared__ int4   s_d[CROP_HW];   // {topOff = ti*W+li, dR = ri-li, dB = (bi-ti)*W, unused}
    __shared__ float4 s_w[CROP_HW];   // {ly, lx, validFloat, unused}
    __shared__ int s_n, s_b;

    // Bijective XCD swizzle: each XCD gets a contiguous chunk-major range.
    const int nwg = gridDim.x;
    int wgid = blockIdx.x;
    if ((nwg % NXCD) == 0) {
        const int per = nwg / NXCD;
        wgid = (wgid % NXCD) * per + wgid / NXCD;
    }
    // Chunk-major: consecutive wgid -> consecutive sorted slots within a chunk.
    const int chunk = wgid / N;
    const int slot  = wgid - chunk * N;
    const int t     = threadIdx.x;

    if (t == 0) {
        const int n = perm[slot];
        s_n = n;
        s_b = box_ind[n];
    }
    __syncthreads();
    const int n = s_n;

    if (t < CROP_HW) {
        const int iy = t / CROP_W;
        const int ix = t - iy * CROP_W;
        const float y1 = boxes[n * 4 + 0];
        const float x1 = boxes[n * 4 + 1];
        const float y2 = boxes[n * 4 + 2];
        const float x2 = boxes[n * 4 + 3];

        const float hs   = (y2 - y1) * (float)(H_DIM - 1) / (float)(CROP_H - 1);
        const float ws   = (x2 - x1) * (float)(W_DIM - 1) / (float)(CROP_W - 1);
        const float in_y = y1 * (float)(H_DIM - 1) + (float)iy * hs;
        const float in_x = x1 * (float)(W_DIM - 1) + (float)ix * ws;

        const int vy = (in_y >= 0.0f) && (in_y <= (float)(H_DIM - 1));
        const int vx = (in_x >= 0.0f) && (in_x <= (float)(W_DIM - 1));

        const float top  = floorf(in_y);
        const float left = floorf(in_x);
        const float ly   = in_y - top;    // from UNclipped floor (matches ref)
        const float lx   = in_x - left;

        int ti = (int)top;
        ti = min(max(ti, 0), H_DIM - 1);
        const int bi = min(ti + 1, H_DIM - 1);
        int li = (int)left;
        li = min(max(li, 0), W_DIM - 1);
        const int ri = min(li + 1, W_DIM - 1);

        s_d[t] = make_int4(ti * W_DIM + li, ri - li, (bi - ti) * W_DIM, 0);
        s_w[t] = make_float4(ly, lx, (vy & vx) ? 1.0f : 0.0f, 0.0f);
    }
    __syncthreads();

    const float* __restrict__ imgb = image + (size_t)s_b * (C_DIM * HW)
                                           + (size_t)chunk * (C_PER * HW);
    float* __restrict__ outb = out + (size_t)n * PER_BOX + (size_t)chunk * ELEMS;

    for (int g = 0; g < ITERS / GRP; ++g) {
        float tl0, tr0, bl0, br0, tl1, tr1, bl1, br1;
        float tl2, tr2, bl2, br2, tl3, tr3, bl3, br3;
        float tl4, tr4, bl4, br4, tl5, tr5, bl5, br5;
        float tl6, tr6, bl6, br6;

        // Phase A: issue all 28 gathers back-to-back (plain C loads).
        GATHER(0, tl0, tr0, bl0, br0);
        GATHER(1, tl1, tr1, bl1, br1);
        GATHER(2, tl2, tr2, bl2, br2);
        GATHER(3, tl3, tr3, bl3, br3);
        GATHER(4, tl4, tr4, bl4, br4);
        GATHER(5, tl5, tr5, bl5, br5);
        GATHER(6, tl6, tr6, bl6, br6);

        // Register anchor: all 28 results are operands of ONE asm ->
        // simultaneously live, loads cannot sink past it, waitcnt batched.
        asm volatile(""
            : "+v"(tl0), "+v"(tr0), "+v"(bl0), "+v"(br0),
              "+v"(tl1), "+v"(tr1), "+v"(bl1), "+v"(br1),
              "+v"(tl2), "+v"(tr2), "+v"(bl2), "+v"(br2),
              "+v"(tl3), "+v"(tr3), "+v"(bl3), "+v"(br3),
              "+v"(tl4), "+v"(tr4), "+v"(bl4), "+v"(br4),
              "+v"(tl5), "+v"(tr5), "+v"(bl5), "+v"(br5),
              "+v"(tl6), "+v"(tr6), "+v"(bl6), "+v"(br6));

        // Phase C: consume + store.
        CONSUME(0, tl0, tr0, bl0, br0);
        CONSUME(1, tl1, tr1, bl1, br1);
        CONSUME(2, tl2, tr2, bl2, br2);
        CONSUME(3, tl3, tr3, bl3, br3);
        CONSUME(4, tl4, tr4, bl4, br4);
        CONSUME(5, tl5, tr5, bl5, br5);
        CONSUME(6, tl6, tr6, bl6, br6);
    }
}

extern "C" void kernel_launch(void* const* d_in, const int* in_sizes, int n_in,
                              void* d_out, int out_size, void* d_ws, size_t ws_size,
                              hipStream_t stream) {
    const float* image   = (const float*)d_in[0];
    const float* boxes   = (const float*)d_in[1];
    const int*   box_ind = (const int*)d_in[2];
    float*       out     = (float*)d_out;
    int*         perm    = (int*)d_ws;          // N ints of scratch

    const int N = in_sizes[2];  // number of boxes (1000)

    sort_boxes_kernel<<<dim3(1), dim3(BLOCK), 0, stream>>>(box_ind, N, perm);
    crop_and_resize_kernel<<<dim3(N * CHUNKS), dim3(BLOCK), 0, stream>>>(
        image, boxes, box_ind, perm, out, N);
}